// Round 10
// baseline (403.883 us; speedup 1.0000x reference)
//
#include <hip/hip_runtime.h>
#include <math.h>

#define T_SEQ 1024
#define BSZ   8
#define EMB   1280
#define NH    20
#define HD    64
#define MROWS 8192
#define KBYTES (EMB * 2)
#define NKT   20          // K tiles of 64: 1280/64

typedef __attribute__((ext_vector_type(8))) short bf16x8;
typedef __attribute__((ext_vector_type(4))) float f32x4;

__device__ __forceinline__ short f2bf(float f) {
    unsigned u = __float_as_uint(f);
    u += 0x7fff + ((u >> 16) & 1);           // RNE
    return (short)(u >> 16);
}
__device__ __forceinline__ float bf2f(short s) {
    return __uint_as_float(((unsigned)(unsigned short)s) << 16);
}

// async global->LDS, 16B per lane; LDS dest wave-uniform base + lane*16
__device__ __forceinline__ void gld16(const void* g, void* l) {
    __builtin_amdgcn_global_load_lds(
        (const __attribute__((address_space(1))) void*)g,
        (__attribute__((address_space(3))) void*)l, 16, 0, 0);
}

// ---------------------------------------------------------------------------
// fp32 -> bf16 cast (activations), vectorized
// ---------------------------------------------------------------------------
__global__ __launch_bounds__(256) void f2bf_kernel(
    const float* __restrict__ in, short* __restrict__ out, int n8)
{
    int i = blockIdx.x * 256 + threadIdx.x;
    if (i >= n8) return;
    const float4* p = (const float4*)in;
    float4 x = p[2 * i], y = p[2 * i + 1];
    bf16x8 o;
    o[0] = f2bf(x.x); o[1] = f2bf(x.y); o[2] = f2bf(x.z); o[3] = f2bf(x.w);
    o[4] = f2bf(y.x); o[5] = f2bf(y.y); o[6] = f2bf(y.z); o[7] = f2bf(y.w);
    ((bf16x8*)out)[i] = o;
}

// all four weight matrices in one launch (blockIdx.y selects)
__global__ __launch_bounds__(256) void wcast_kernel(
    const float* __restrict__ w0, const float* __restrict__ w1,
    const float* __restrict__ w2, const float* __restrict__ w3,
    short* __restrict__ o0, short* __restrict__ o1,
    short* __restrict__ o2, short* __restrict__ o3, int n8)
{
    int which = blockIdx.y;
    const float* in = (which == 0) ? w0 : (which == 1) ? w1 : (which == 2) ? w2 : w3;
    short* out      = (which == 0) ? o0 : (which == 1) ? o1 : (which == 2) ? o2 : o3;
    int i = blockIdx.x * 256 + threadIdx.x;
    if (i >= n8) return;
    const float4* p = (const float4*)in;
    float4 x = p[2 * i], y = p[2 * i + 1];
    bf16x8 o;
    o[0] = f2bf(x.x); o[1] = f2bf(x.y); o[2] = f2bf(x.z); o[3] = f2bf(x.w);
    o[4] = f2bf(y.x); o[5] = f2bf(y.y); o[6] = f2bf(y.z); o[7] = f2bf(y.w);
    ((bf16x8*)out)[i] = o;
}

// ---------------------------------------------------------------------------
// RoPE cos/sin tables [T_SEQ][32], fp32
// ---------------------------------------------------------------------------
__global__ void rope_table_kernel(float* __restrict__ cost, float* __restrict__ sint) {
    int idx = blockIdx.x * 256 + threadIdx.x;
    if (idx >= T_SEQ * 32) return;
    int i = idx & 31, t = idx >> 5;
    float inv = powf(10000.0f, -(float)i / 32.0f);
    float f = (float)t * inv;
    cost[idx] = cosf(f);
    sint[idx] = sinf(f);
}

// ---------------------------------------------------------------------------
// MFMA GEMM core, counted-vmcnt pipeline (T4).  C(256x128) = A * B^T, BK=64.
// 2 LDS slots (A 32KB + B 16KB each, 96KB total), 2 K-tiles in flight:
//   iter t: compute tile t from slot[t&1]; barrier (reads done); stage tile
//   t+2 into slot[t&1]; vmcnt(6) -> tile t+1 landed (t+2's 6 loads still in
//   flight ACROSS the barrier); barrier.  No vmcnt(0) drain in steady state.
// Raw s_barrier (no waitcnt) + asm memory fences; compute uses plain C++
// loads so the compiler inserts its own lgkmcnt before MFMA use.
// 8 waves (4M x 2N), wave tile 64x64 -- fragment math identical to the
// proven 128x128 core.  XOR-swizzle (T2) unchanged; setprio (T5) on MFMA.
// ---------------------------------------------------------------------------
__device__ __forceinline__ void gemm_stage(
    const short* __restrict__ A, const short* __restrict__ B,
    char* As, char* Bs, int m0, int n0, int k0, int w, int srow, int scol)
{
    #pragma unroll
    for (int c = 0; c < 4; ++c) {
        int ch = w * 4 + c;                  // 0..31  (256 A rows / 8)
        int row = ch * 8 + srow;
        gld16((const char*)A + (size_t)(m0 + row) * KBYTES + k0 * 2 + scol,
              As + ch * 1024);
    }
    #pragma unroll
    for (int c = 0; c < 2; ++c) {
        int ch = w * 2 + c;                  // 0..15  (128 B rows / 8)
        int row = ch * 8 + srow;
        gld16((const char*)B + (size_t)(n0 + row) * KBYTES + k0 * 2 + scol,
              Bs + ch * 1024);
    }
}

__device__ __forceinline__ void gemm_core512(
    const short* __restrict__ A, const short* __restrict__ B,
    char* As0, char* Bs0, char* As1, char* Bs1,
    int m0, int n0, int tid, f32x4 (&acc)[4][4])
{
    const int l   = tid & 63;
    const int w   = tid >> 6;                // 0..7
    const int wr  = w >> 1, wc = w & 1;

    const int srow = l >> 3;
    const int scol = ((l & 7) ^ srow) << 4;  // inverse-swizzled src col byte
    const int g16  = (l >> 4) << 4;
    const int swx  = (l & 7) << 4;           // read-side XOR (row&7)<<4

    // prologue: tiles 0 and 1 in flight; verify tile 0 only (6 newest stay out)
    gemm_stage(A, B, As0, Bs0, m0, n0, 0,  w, srow, scol);
    gemm_stage(A, B, As1, Bs1, m0, n0, 64, w, srow, scol);
    asm volatile("s_waitcnt vmcnt(6)" ::: "memory");
    __builtin_amdgcn_s_barrier();
    asm volatile("" ::: "memory");

    for (int t = 0; t < NKT; ++t) {
        char* As = (t & 1) ? As1 : As0;
        char* Bs = (t & 1) ? Bs1 : Bs0;

        #pragma unroll
        for (int kk = 0; kk < 2; ++kk) {
            const int cb = (kk * 64 + g16) ^ swx;
            bf16x8 af[4], bfr[4];
            #pragma unroll
            for (int m = 0; m < 4; ++m)
                af[m] = *(const bf16x8*)(As + (wr * 64 + m * 16 + (l & 15)) * 128 + cb);
            #pragma unroll
            for (int n = 0; n < 4; ++n)
                bfr[n] = *(const bf16x8*)(Bs + (wc * 64 + n * 16 + (l & 15)) * 128 + cb);
            __builtin_amdgcn_s_setprio(1);
            #pragma unroll
            for (int m = 0; m < 4; ++m)
                #pragma unroll
                for (int n = 0; n < 4; ++n)
                    acc[m][n] = __builtin_amdgcn_mfma_f32_16x16x32_bf16(
                        af[m], bfr[n], acc[m][n], 0, 0, 0);
            __builtin_amdgcn_s_setprio(0);
        }

        asm volatile("" ::: "memory");
        __builtin_amdgcn_s_barrier();        // all waves done reading slot[t&1]
        asm volatile("" ::: "memory");

        if (t + 2 < NKT)
            gemm_stage(A, B, As, Bs, m0, n0, (t + 2) * 64, w, srow, scol);

        if (t + 2 < NKT) { asm volatile("s_waitcnt vmcnt(6)" ::: "memory"); }
        else             { asm volatile("s_waitcnt vmcnt(0)" ::: "memory"); }
        __builtin_amdgcn_s_barrier();        // collective: tile t+1 landed
        asm volatile("" ::: "memory");
    }
}

// ---------------------------------------------------------------------------
// QKV projection (z selects Q/K/V): bias + RoPE (z<2) fused in fp32 epilogue,
// bf16 out scattered to [B,H,T,D]; Q pre-scaled by 1/8.
// ---------------------------------------------------------------------------
__global__ __launch_bounds__(512) void qkv_gemm_kernel(
    const short* __restrict__ A,
    const short* __restrict__ B0, const short* __restrict__ B1, const short* __restrict__ B2,
    const float* __restrict__ bias0, const float* __restrict__ bias1, const float* __restrict__ bias2,
    const float* __restrict__ cost, const float* __restrict__ sint,
    short* __restrict__ O0, short* __restrict__ O1, short* __restrict__ O2)
{
    __shared__ short As0_s[16384];
    __shared__ short Bs0_s[8192];
    __shared__ short As1_s[16384];
    __shared__ short Bs1_s[8192];

    const int z = blockIdx.z;
    const short* B = (z == 0) ? B0 : (z == 1) ? B1 : B2;
    const float* bias = (z == 0) ? bias0 : (z == 1) ? bias1 : bias2;
    short* O = (z == 0) ? O0 : (z == 1) ? O1 : O2;
    const float scale = (z == 0) ? 0.125f : 1.0f;

    const int tid = threadIdx.x;
    const int l = tid & 63;
    const int wid = tid >> 6;
    const int wr = wid >> 1, wc = wid & 1;
    const int m0 = blockIdx.x * 256;
    const int n0 = blockIdx.y * 128;

    f32x4 acc[4][4];
    const f32x4 z4 = {0.f, 0.f, 0.f, 0.f};
    #pragma unroll
    for (int m = 0; m < 4; ++m)
        #pragma unroll
        for (int n = 0; n < 4; ++n) acc[m][n] = z4;

    gemm_core512(A, B, (char*)As0_s, (char*)Bs0_s, (char*)As1_s, (char*)Bs1_s,
                 m0, n0, tid, acc);

    // bias (before rotation, like reference)
    #pragma unroll
    for (int n = 0; n < 4; ++n) {
        int col = n0 + wc * 64 + n * 16 + (l & 15);
        float bv = bias[col];
        #pragma unroll
        for (int m = 0; m < 4; ++m)
            #pragma unroll
            for (int r = 0; r < 4; ++r) acc[m][n][r] += bv;
    }

    // fused RoPE for Q,K: pairs (d, d+32) = (acc[.][n], acc[.][n+2]), n=0,1
    if (z < 2) {
        #pragma unroll
        for (int m = 0; m < 4; ++m) {
            #pragma unroll
            for (int r = 0; r < 4; ++r) {
                int row = m0 + wr * 64 + m * 16 + (l >> 4) * 4 + r;
                int t = row >> 3;
                #pragma unroll
                for (int n = 0; n < 2; ++n) {
                    int i = n * 16 + (l & 15);
                    float c = cost[t * 32 + i];
                    float s = sint[t * 32 + i];
                    float x1 = acc[m][n][r], x2 = acc[m][n + 2][r];
                    acc[m][n][r]     = x1 * c - x2 * s;
                    acc[m][n + 2][r] = x2 * c + x1 * s;
                }
            }
        }
    }

    #pragma unroll
    for (int n = 0; n < 4; ++n) {
        int col = n0 + wc * 64 + n * 16 + (l & 15);
        int h = col >> 6, d = col & 63;
        #pragma unroll
        for (int m = 0; m < 4; ++m) {
            #pragma unroll
            for (int r = 0; r < 4; ++r) {
                int row = m0 + wr * 64 + m * 16 + (l >> 4) * 4 + r;
                int t = row >> 3, b = row & 7;
                O[((size_t)(b * NH + h) * T_SEQ + t) * HD + d] = f2bf(acc[m][n][r] * scale);
            }
        }
    }
}

// ---------------------------------------------------------------------------
// Output projection: fp32 out [T,B,E] + bias
// ---------------------------------------------------------------------------
__global__ __launch_bounds__(512) void out_gemm_kernel(
    const short* __restrict__ A, const short* __restrict__ B,
    const float* __restrict__ bias, float* __restrict__ O)
{
    __shared__ short As0_s[16384];
    __shared__ short Bs0_s[8192];
    __shared__ short As1_s[16384];
    __shared__ short Bs1_s[8192];

    const int tid = threadIdx.x;
    const int l = tid & 63;
    const int wid = tid >> 6;
    const int wr = wid >> 1, wc = wid & 1;
    const int m0 = blockIdx.x * 256;
    const int n0 = blockIdx.y * 128;

    f32x4 acc[4][4];
    const f32x4 z4 = {0.f, 0.f, 0.f, 0.f};
    #pragma unroll
    for (int m = 0; m < 4; ++m)
        #pragma unroll
        for (int n = 0; n < 4; ++n) acc[m][n] = z4;

    gemm_core512(A, B, (char*)As0_s, (char*)Bs0_s, (char*)As1_s, (char*)Bs1_s,
                 m0, n0, tid, acc);

    #pragma unroll
    for (int n = 0; n < 4; ++n) {
        int col = n0 + wc * 64 + n * 16 + (l & 15);
        float bv = bias[col];
        #pragma unroll
        for (int m = 0; m < 4; ++m) {
            #pragma unroll
            for (int r = 0; r < 4; ++r) {
                int row = m0 + wr * 64 + m * 16 + (l >> 4) * 4 + r;
                O[(size_t)row * EMB + col] = acc[m][n][r] + bv;
            }
        }
    }
}

// ---------------------------------------------------------------------------
// V transpose per bh: [bh][t][d] -> [bh][d][t]
// ---------------------------------------------------------------------------
__global__ __launch_bounds__(256) void transpose_v_kernel(
    const short* __restrict__ v, short* __restrict__ vt)
{
    __shared__ short tv[64][72];
    const int tid = threadIdx.x;
    const int bh = blockIdx.y, t0 = blockIdx.x * 64;
    const short* src = v + ((size_t)bh * T_SEQ + t0) * HD;
    #pragma unroll
    for (int p = 0; p < 2; ++p) {
        int row = p * 32 + (tid >> 3);
        int c8 = (tid & 7) * 8;
        *(bf16x8*)&tv[row][c8] = *(const bf16x8*)(src + row * HD + c8);
    }
    __syncthreads();
    short* dst = vt + (size_t)bh * (HD * T_SEQ) + t0;
    #pragma unroll
    for (int p = 0; p < 2; ++p) {
        int d = p * 32 + (tid >> 3);
        int t8 = (tid & 7) * 8;
        bf16x8 o;
        #pragma unroll
        for (int j = 0; j < 8; ++j) o[j] = tv[t8 + j][d];
        *(bf16x8*)(dst + (size_t)d * T_SEQ + t8) = o;
    }
}

// ---------------------------------------------------------------------------
// Flash attention (frozen from R9): swapped QK^T lane-local softmax, packed
// P-writes, defer-max, Q staged through Ps (40KB LDS), dbuf K/V, XCD swizzle.
// ---------------------------------------------------------------------------
__global__ __launch_bounds__(256) void attn_kernel(
    const short* __restrict__ Q, const short* __restrict__ K,
    const short* __restrict__ Vt, short* __restrict__ Aout)
{
    __shared__ short Ks_s[8192];
    __shared__ short Vs_s[8192];
    __shared__ short Ps_s[4096];    // doubles as the Q staging buffer
    char* Ks = (char*)Ks_s;
    char* Vs = (char*)Vs_s;
    char* Ps = (char*)Ps_s;

    const int tid = threadIdx.x;
    const int l = tid & 63;
    const int w = tid >> 6;
    const int g = l >> 4;               // 16-lane group 0..3

    // XCD swizzle: 16*160 = 2560 blocks, 320 per XCD chunk
    const int bid = blockIdx.y * 16 + blockIdx.x;
    const int swz = (bid & 7) * 320 + (bid >> 3);
    const int q0 = (swz & 15) * 64;
    const int bh = swz >> 4;

    const int srow = l >> 3;
    const int scol = ((l & 7) ^ srow) << 4;
    const int g16  = g << 4;
    const int swx  = (l & 7) << 4;      // read XOR for LDS rows (row&7)==(l&7)

    const short* Qg = Q + (size_t)bh * (T_SEQ * HD);
    const short* Kg = K + (size_t)bh * (T_SEQ * HD);
    const short* Vg = Vt + (size_t)bh * (HD * T_SEQ);

    // prologue: Q tile -> Ps; K/V tile 0 -> buf 0
    #pragma unroll
    for (int c = 0; c < 2; ++c) {
        int ch = w * 2 + c;
        int row = ch * 8 + srow;
        gld16((const char*)Qg + (size_t)(q0 + row) * HD * 2 + scol, Ps + ch * 1024);
        gld16((const char*)Kg + (size_t)(row) * HD * 2 + scol, Ks + ch * 1024);
        gld16((const char*)Vg + ((size_t)row * T_SEQ) * 2 + scol, Vs + ch * 1024);
    }
    __syncthreads();

    // hoist Q fragments (row = w*16 + (l&15)) into registers for all 16 tiles
    bf16x8 qf[2];
    #pragma unroll
    for (int kk = 0; kk < 2; ++kk)
        qf[kk] = *(const bf16x8*)(Ps + (w * 16 + (l & 15)) * 128 + ((kk * 64 + g16) ^ swx));

    f32x4 oacc[4];
    const f32x4 z4 = {0.f, 0.f, 0.f, 0.f};
    #pragma unroll
    for (int n = 0; n < 4; ++n) oacc[n] = z4;
    float m_i = -INFINITY;   // running max of q-row (l&15), replicated over g
    float l_i = 0.f;         // running sum, same row

    const int pbase = (w * 16 + (l & 15)) * 128;   // P row byte base (wave-local)

    int buf = 0;
    for (int kt = 0; kt < T_SEQ / 64; ++kt) {
        // issue next tile's loads FIRST (latency hides under compute below)
        if (kt + 1 < T_SEQ / 64) {
            const int ob = (buf ^ 1) * 8192;
            #pragma unroll
            for (int c = 0; c < 2; ++c) {
                int ch = w * 2 + c;
                int row = ch * 8 + srow;
                gld16((const char*)Kg + (size_t)((kt + 1) * 64 + row) * HD * 2 + scol,
                      Ks + ob + ch * 1024);
                gld16((const char*)Vg + ((size_t)row * T_SEQ + (kt + 1) * 64) * 2 + scol,
                      Vs + ob + ch * 1024);
            }
        }
        const int cbuf = buf * 8192;

        // ---- swapped QK^T: sT[n] rows = kv (n*16 + g*4 + r), col = q (l&15) ----
        f32x4 sT[4];
        #pragma unroll
        for (int n = 0; n < 4; ++n) sT[n] = z4;
        __builtin_amdgcn_s_setprio(1);
        #pragma unroll
        for (int kk = 0; kk < 2; ++kk) {
            const int cb = (kk * 64 + g16) ^ swx;
            #pragma unroll
            for (int n = 0; n < 4; ++n) {
                bf16x8 kf = *(const bf16x8*)(Ks + cbuf + (n * 16 + (l & 15)) * 128 + cb);
                sT[n] = __builtin_amdgcn_mfma_f32_16x16x32_bf16(kf, qf[kk], sT[n], 0, 0, 0);
            }
        }
        __builtin_amdgcn_s_setprio(0);

        // ---- lane-local softmax (lane owns q-row l&15; 16 kv values) ----
        float pmax = fmaxf(fmaxf(sT[0][0], sT[0][1]), fmaxf(sT[0][2], sT[0][3]));
        #pragma unroll
        for (int n = 1; n < 4; ++n)
            pmax = fmaxf(pmax, fmaxf(fmaxf(sT[n][0], sT[n][1]), fmaxf(sT[n][2], sT[n][3])));
        pmax = fmaxf(pmax, __shfl_xor(pmax, 16));
        pmax = fmaxf(pmax, __shfl_xor(pmax, 32));

        if (__any(pmax > m_i + 8.0f)) {            // defer-max: rescale rarely
            float mn = fmaxf(m_i, pmax);
            float corr = __expf(m_i - mn);
            m_i = mn;
            l_i *= corr;
            #pragma unroll
            for (int r = 0; r < 4; ++r) {
                float cp = __shfl(corr, (l & 48) | (g * 4 + r));  // corr of oacc row
                #pragma unroll
                for (int n = 0; n < 4; ++n) oacc[n][r] *= cp;
            }
        }

        float lsum = 0.f;
        #pragma unroll
        for (int n = 0; n < 4; ++n) {
            float p0 = __expf(sT[n][0] - m_i);
            float p1 = __expf(sT[n][1] - m_i);
            float p2 = __expf(sT[n][2] - m_i);
            float p3 = __expf(sT[n][3] - m_i);
            lsum += (p0 + p1) + (p2 + p3);
            unsigned lo = ((unsigned)(unsigned short)f2bf(p0)) |
                          (((unsigned)(unsigned short)f2bf(p1)) << 16);
            unsigned hi = ((unsigned)(unsigned short)f2bf(p2)) |
                          (((unsigned)(unsigned short)f2bf(p3)) << 16);
            uint2 pk; pk.x = lo; pk.y = hi;
            // elements kv = n*16 + g*4 + {0..3} at byte (kv*2) ^ ((row&7)<<4)
            *(uint2*)(Ps + pbase + ((n * 32 + g * 8) ^ swx)) = pk;
        }
        lsum += __shfl_xor(lsum, 16);
        lsum += __shfl_xor(lsum, 32);
        l_i += lsum;

        // ---- PV: M=16 (q-rows), N=64 (d), K=64 (kv); A=P (wave-local), B=Vt ----
        __builtin_amdgcn_s_setprio(1);
        #pragma unroll
        for (int kk = 0; kk < 2; ++kk) {
            const int cb = (kk * 64 + g16) ^ swx;
            bf16x8 ap = *(const bf16x8*)(Ps + pbase + cb);
            #pragma unroll
            for (int n = 0; n < 4; ++n) {
                bf16x8 bv = *(const bf16x8*)(Vs + cbuf + (n * 16 + (l & 15)) * 128 + cb);
                oacc[n] = __builtin_amdgcn_mfma_f32_16x16x32_bf16(ap, bv, oacc[n], 0, 0, 0);
            }
        }
        __builtin_amdgcn_s_setprio(0);

        __syncthreads();   // drains prefetch vmcnt + syncs waves; next tile ready
        buf ^= 1;
    }

    // epilogue: normalize (1/l_i broadcast to oacc rows) and write [T,B,E]
    float inv = 1.0f / l_i;
    float invp[4];
    #pragma unroll
    for (int r = 0; r < 4; ++r) invp[r] = __shfl(inv, (l & 48) | (g * 4 + r));

    const int b_ = bh / NH, h = bh % NH;
    #pragma unroll
    for (int n = 0; n < 4; ++n) {
        int d = h * HD + n * 16 + (l & 15);
        #pragma unroll
        for (int r = 0; r < 4; ++r) {
            int t = q0 + w * 16 + g * 4 + r;
            Aout[((size_t)t * BSZ + b_) * EMB + d] = f2bf(oacc[n][r] * invp[r]);
        }
    }
}

// ---------------------------------------------------------------------------
extern "C" void kernel_launch(void* const* d_in, const int* in_sizes, int n_in,
                              void* d_out, int out_size, void* d_ws, size_t ws_size,
                              hipStream_t stream) {
    const float* X     = (const float*)d_in[0];
    const float* q_w   = (const float*)d_in[1];
    const float* q_b   = (const float*)d_in[2];
    const float* k_w   = (const float*)d_in[3];
    const float* k_b   = (const float*)d_in[4];
    const float* v_w   = (const float*)d_in[5];
    const float* v_b   = (const float*)d_in[6];
    const float* out_w = (const float*)d_in[7];
    const float* out_b = (const float*)d_in[8];
    float* out = (float*)d_out;

    short* ws = (short*)d_ws;
    const size_t NACT = (size_t)MROWS * EMB;        // 10485760
    const size_t NW   = (size_t)EMB * EMB;          // 1638400
    short* xb  = ws;
    short* wqb = xb + NACT;
    short* wkb = wqb + NW;
    short* wvb = wkb + NW;
    short* wob = wvb + NW;
    short* qb  = wob + NW;
    short* kb  = qb + NACT;
    short* vb  = kb + NACT;
    short* vtb = vb + NACT;
    short* ab  = vtb + NACT;
    float* cost = (float*)(ab + NACT);
    float* sint = cost + T_SEQ * 32;

    rope_table_kernel<<<dim3(128), 256, 0, stream>>>(cost, sint);
    f2bf_kernel<<<dim3(5120), 256, 0, stream>>>(X, xb, (int)(NACT / 8));
    wcast_kernel<<<dim3(800, 4), 256, 0, stream>>>(
        q_w, k_w, v_w, out_w, wqb, wkb, wvb, wob, (int)(NW / 8));

    qkv_gemm_kernel<<<dim3(MROWS / 256, EMB / 128, 3), 512, 0, stream>>>(
        xb, wqb, wkb, wvb, q_b, k_b, v_b, cost, sint, qb, kb, vb);

    transpose_v_kernel<<<dim3(T_SEQ / 64, BSZ * NH), 256, 0, stream>>>(vb, vtb);

    attn_kernel<<<dim3(T_SEQ / 64, BSZ * NH), 256, 0, stream>>>(qb, kb, vtb, ab);

    out_gemm_kernel<<<dim3(MROWS / 256, EMB / 128), 512, 0, stream>>>(
        ab, wob, out_b, out);
}